// Round 8
// baseline (677.233 us; speedup 1.0000x reference)
//
#include <hip/hip_runtime.h>

// ---------------------------------------------------------------------------
// GCN 2-layer forward, f32 — CSR-gather, XCD-privatized degree histograms.
//
// hist: 8 private copies (one per XCD), indexed via s_getreg(HW_REG_XCC_ID),
//       updated with WORKGROUP-scope atomics (no sc1 -> RMW stays in the
//       XCD-local L2, no 32B/op fabric write-through). Reduced + fused into
//       norms afterwards. Copies overlap agg1's workspace (consumed first).
// ---------------------------------------------------------------------------

__global__ __launch_bounds__(256)
void hist8_int(const int* __restrict__ src, const int* __restrict__ dst,
               int* __restrict__ hist_out, int* __restrict__ hist_in, // [8][N]
               int N, int E)
{
    unsigned xcc;
    asm volatile("s_getreg_b32 %0, hwreg(HW_REG_XCC_ID)" : "=s"(xcc));
    xcc &= 7;
    int* ho = hist_out + (size_t)xcc * N;
    int* hi = hist_in  + (size_t)xcc * N;
    int stride = gridDim.x * 256;
    for (int e = blockIdx.x * 256 + threadIdx.x; e < E; e += stride) {
        __hip_atomic_fetch_add(&ho[src[e]], 1, __ATOMIC_RELAXED,
                               __HIP_MEMORY_SCOPE_WORKGROUP);
        __hip_atomic_fetch_add(&hi[dst[e]], 1, __ATOMIC_RELAXED,
                               __HIP_MEMORY_SCOPE_WORKGROUP);
    }
}

// reduce the 8 copies; emit int deg_in (for the scan) and both norms
__global__ __launch_bounds__(256)
void reduce_norms(const int* __restrict__ hist_out, const int* __restrict__ hist_in,
                  int* __restrict__ deg_in, float* __restrict__ norm_out,
                  float* __restrict__ norm_in, int N)
{
    int n = blockIdx.x * 256 + threadIdx.x;
    if (n >= N) return;
    int so = 0, si = 0;
    #pragma unroll
    for (int c = 0; c < 8; ++c) {
        so += hist_out[(size_t)c * N + n];
        si += hist_in[(size_t)c * N + n];
    }
    deg_in[n] = si;
    norm_out[n] = 1.0f / sqrtf((float)(so > 1 ? so : 1));
    norm_in[n]  = 1.0f / sqrtf((float)(si > 1 ? si : 1));
}

// ---- 3-kernel exclusive scan over deg_in (chunk = 1024 elems/block) -------
__global__ __launch_bounds__(256)
void scan_block_sums(const int* __restrict__ deg, int* __restrict__ blockSums, int N)
{
    int t = threadIdx.x;
    int base = blockIdx.x * 1024 + t * 4;
    int s = 0;
    #pragma unroll
    for (int i = 0; i < 4; ++i) { int idx = base + i; if (idx < N) s += deg[idx]; }
    #pragma unroll
    for (int d = 32; d > 0; d >>= 1) s += __shfl_down(s, d);
    __shared__ int ws[4];
    int wid = t >> 6, lane = t & 63;
    if (lane == 0) ws[wid] = s;
    __syncthreads();
    if (t == 0) blockSums[blockIdx.x] = ws[0] + ws[1] + ws[2] + ws[3];
}

__global__ void scan_offsets(const int* __restrict__ blockSums, int* __restrict__ blockOffs,
                             int NB, int* __restrict__ row_start, int N, int E)
{
    if (threadIdx.x == 0 && blockIdx.x == 0) {
        int run = 0;
        for (int b = 0; b < NB; ++b) { blockOffs[b] = run; run += blockSums[b]; }
        row_start[N] = E;
    }
}

__global__ __launch_bounds__(256)
void scan_write(const int* __restrict__ deg, const int* __restrict__ blockOffs,
                int* __restrict__ row_start, int* __restrict__ cursor, int N)
{
    int t = threadIdx.x, lane = t & 63, wid = t >> 6;
    int base = blockIdx.x * 1024 + t * 4;
    int v[4]; int s = 0;
    #pragma unroll
    for (int i = 0; i < 4; ++i) {
        int idx = base + i;
        v[i] = (idx < N) ? deg[idx] : 0;
        s += v[i];
    }
    int x = s;
    #pragma unroll
    for (int d = 1; d < 64; d <<= 1) { int y = __shfl_up(x, d); if (lane >= d) x += y; }
    __shared__ int wtot[4];
    if (lane == 63) wtot[wid] = x;
    __syncthreads();
    int woff = 0;
    for (int w = 0; w < wid; ++w) woff += wtot[w];
    int run = (x - s) + woff + blockOffs[blockIdx.x];
    #pragma unroll
    for (int i = 0; i < 4; ++i) {
        int idx = base + i;
        if (idx < N) { row_start[idx] = run; cursor[idx] = run; run += v[i]; }
    }
}

__global__ __launch_bounds__(256)
void fill_perm(const int* __restrict__ src, const int* __restrict__ dst,
               int* __restrict__ cursor, int* __restrict__ perm, int E)
{
    int e = blockIdx.x * 256 + threadIdx.x;
    if (e < E) {
        int pos = atomicAdd(&cursor[dst[e]], 1);   // device scope: global position
        perm[pos] = src[e];
    }
}

// 128-ch gather: half-wave (32 lanes) x float4 covers one 512B row.
__global__ __launch_bounds__(256)
void gather_agg128(const float* __restrict__ X, const int* __restrict__ perm,
                   const int* __restrict__ row_start, const float* __restrict__ norm_out,
                   float* __restrict__ out, int N)
{
    int wid = threadIdx.x >> 6, lane = threadIdx.x & 63;
    int n = blockIdx.x * 4 + wid;
    if (n >= N) return;
    int half = lane >> 5;
    int sub  = lane & 31;
    const float4* X4 = (const float4*)X;
    int e = row_start[n], e1 = row_start[n + 1];
    float4 acc = make_float4(0.f, 0.f, 0.f, 0.f);

    for (; e + 4 <= e1; e += 4) {
        int a = perm[e + half];
        int b = perm[e + 2 + half];
        float wa = norm_out[a], wb = norm_out[b];
        float4 va = X4[(size_t)a * 32 + sub];
        float4 vb = X4[(size_t)b * 32 + sub];
        acc.x = fmaf(va.x, wa, fmaf(vb.x, wb, acc.x));
        acc.y = fmaf(va.y, wa, fmaf(vb.y, wb, acc.y));
        acc.z = fmaf(va.z, wa, fmaf(vb.z, wb, acc.z));
        acc.w = fmaf(va.w, wa, fmaf(vb.w, wb, acc.w));
    }
    for (; e + 2 <= e1; e += 2) {
        int a = perm[e + half];
        float wa = norm_out[a];
        float4 va = X4[(size_t)a * 32 + sub];
        acc.x = fmaf(va.x, wa, acc.x);
        acc.y = fmaf(va.y, wa, acc.y);
        acc.z = fmaf(va.z, wa, acc.z);
        acc.w = fmaf(va.w, wa, acc.w);
    }
    if (e < e1 && half == 0) {
        int a = perm[e];
        float wa = norm_out[a];
        float4 va = X4[(size_t)a * 32 + sub];
        acc.x = fmaf(va.x, wa, acc.x);
        acc.y = fmaf(va.y, wa, acc.y);
        acc.z = fmaf(va.z, wa, acc.z);
        acc.w = fmaf(va.w, wa, acc.w);
    }
    acc.x += __shfl_xor(acc.x, 32);
    acc.y += __shfl_xor(acc.y, 32);
    acc.z += __shfl_xor(acc.z, 32);
    acc.w += __shfl_xor(acc.w, 32);
    if (half == 0)
        ((float4*)out)[(size_t)n * 32 + sub] = acc;
}

// 64-ch gather: quarter-wave (16 lanes) x float4; fused *norm_in + bias.
__global__ __launch_bounds__(256)
void gather_out64(const float* __restrict__ X, const int* __restrict__ perm,
                  const int* __restrict__ row_start, const float* __restrict__ norm_in,
                  const float* __restrict__ bias, float* __restrict__ out, int N)
{
    int wid = threadIdx.x >> 6, lane = threadIdx.x & 63;
    int n = blockIdx.x * 4 + wid;
    if (n >= N) return;
    int q   = lane >> 4;
    int sub = lane & 15;
    const float4* X4 = (const float4*)X;
    int e = row_start[n], e1 = row_start[n + 1];
    float4 acc = make_float4(0.f, 0.f, 0.f, 0.f);

    for (; e + 8 <= e1; e += 8) {
        int a = perm[e + q];
        int b = perm[e + 4 + q];
        float4 va = X4[(size_t)a * 16 + sub];
        float4 vb = X4[(size_t)b * 16 + sub];
        acc.x += va.x + vb.x;
        acc.y += va.y + vb.y;
        acc.z += va.z + vb.z;
        acc.w += va.w + vb.w;
    }
    for (; e + 4 <= e1; e += 4) {
        int a = perm[e + q];
        float4 va = X4[(size_t)a * 16 + sub];
        acc.x += va.x; acc.y += va.y; acc.z += va.z; acc.w += va.w;
    }
    int r = e1 - e;      // 0..3
    if (q < r) {
        int a = perm[e + q];
        float4 va = X4[(size_t)a * 16 + sub];
        acc.x += va.x; acc.y += va.y; acc.z += va.z; acc.w += va.w;
    }
    acc.x += __shfl_xor(acc.x, 32);
    acc.y += __shfl_xor(acc.y, 32);
    acc.z += __shfl_xor(acc.z, 32);
    acc.w += __shfl_xor(acc.w, 32);
    acc.x += __shfl_xor(acc.x, 16);
    acc.y += __shfl_xor(acc.y, 16);
    acc.z += __shfl_xor(acc.z, 16);
    acc.w += __shfl_xor(acc.w, 16);
    if (q == 0) {
        float ni = norm_in[n];
        float4 bv = ((const float4*)bias)[sub];
        float4 o;
        o.x = fmaf(acc.x, ni, bv.x);
        o.y = fmaf(acc.y, ni, bv.y);
        o.z = fmaf(acc.z, ni, bv.z);
        o.w = fmaf(acc.w, ni, bv.w);
        ((float4*)out)[(size_t)n * 16 + sub] = o;
    }
}

// Tiled f32 GEMM: C[M,NC] = A[M,K]@B[K,NC]. BM=128, BK=16, 256 thr.
template<int BN, int TN, int EPI>
__global__ __launch_bounds__(256)
void gemm_tiled(const float* __restrict__ A, const float* __restrict__ B,
                float* __restrict__ C, int M, int K, int NC,
                const float* __restrict__ norm_in,
                const float* __restrict__ norm_out,
                const float* __restrict__ bias)
{
    __shared__ float As[16][132];
    __shared__ float Bs[16][BN];
    const int tid = threadIdx.x;
    const int tx = tid & 15;
    const int ty = tid >> 4;
    const int brow = blockIdx.x * 128;
    const int bcol = blockIdx.y * BN;

    const int ar = tid >> 2;
    const int ak = (tid & 3) * 4;

    float acc[8][TN] = {};

    for (int k0 = 0; k0 < K; k0 += 16) {
        #pragma unroll
        for (int hh = 0; hh < 2; ++hh) {
            int row = ar + hh * 64;
            int grow = brow + row;
            float4 v = make_float4(0.f, 0.f, 0.f, 0.f);
            if (grow < M) v = *(const float4*)(A + (size_t)grow * K + k0 + ak);
            As[ak + 0][row] = v.x;
            As[ak + 1][row] = v.y;
            As[ak + 2][row] = v.z;
            As[ak + 3][row] = v.w;
        }
        if (BN == 128) {
            #pragma unroll
            for (int hh = 0; hh < 2; ++hh) {
                int kr = (tid >> 5) + hh * 8;
                int cc = (tid & 31) * 4;
                *(float4*)&Bs[kr][cc] =
                    *(const float4*)(B + (size_t)(k0 + kr) * NC + bcol + cc);
            }
        } else {
            int kr = tid >> 4;
            int cc = (tid & 15) * 4;
            *(float4*)&Bs[kr][cc] =
                *(const float4*)(B + (size_t)(k0 + kr) * NC + bcol + cc);
        }
        __syncthreads();
        #pragma unroll
        for (int k = 0; k < 16; ++k) {
            float a0[8], b0[TN];
            *(float4*)&a0[0] = *(const float4*)&As[k][ty * 8];
            *(float4*)&a0[4] = *(const float4*)&As[k][ty * 8 + 4];
            *(float4*)&b0[0] = *(const float4*)&Bs[k][tx * TN];
            if (TN == 8)
                *(float4*)&b0[4] = *(const float4*)&Bs[k][tx * TN + 4];
            #pragma unroll
            for (int i = 0; i < 8; ++i)
                #pragma unroll
                for (int j = 0; j < TN; ++j)
                    acc[i][j] = fmaf(a0[i], b0[j], acc[i][j]);
        }
        __syncthreads();
    }

    #pragma unroll
    for (int i = 0; i < 8; ++i) {
        int row = brow + ty * 8 + i;
        if (row >= M) continue;
        float ni = 0.f, no = 0.f;
        if (EPI == 0) { ni = norm_in[row]; no = norm_out[row]; }
        #pragma unroll
        for (int j4 = 0; j4 < TN; j4 += 4) {
            int col = bcol + tx * TN + j4;
            float4 o = *(float4*)&acc[i][j4];
            if (EPI == 0) {
                o.x = fmaxf(fmaf(o.x, ni, bias[col + 0]), 0.0f) * no;
                o.y = fmaxf(fmaf(o.y, ni, bias[col + 1]), 0.0f) * no;
                o.z = fmaxf(fmaf(o.z, ni, bias[col + 2]), 0.0f) * no;
                o.w = fmaxf(fmaf(o.w, ni, bias[col + 3]), 0.0f) * no;
            }
            *(float4*)(C + (size_t)row * NC + col) = o;
        }
    }
}

extern "C" void kernel_launch(void* const* d_in, const int* in_sizes, int n_in,
                              void* d_out, int out_size, void* d_ws, size_t ws_size,
                              hipStream_t stream)
{
    const float* h   = (const float*)d_in[0];
    const int*   src = (const int*)d_in[1];
    const int*   dst = (const int*)d_in[2];
    const float* W1  = (const float*)d_in[3];
    const float* b1  = (const float*)d_in[4];
    const float* W2  = (const float*)d_in[5];
    const float* b2  = (const float*)d_in[6];
    float* out = (float*)d_out;

    const int HID = in_sizes[4];            // 256
    const int OUT = in_sizes[6];            // 64
    const int IN  = in_sizes[3] / HID;      // 128
    const int N   = in_sizes[0] / IN;       // 100000
    const int E   = in_sizes[1];            // 1600000
    const int NB  = (N + 1023) / 1024;

    char* p = (char*)d_ws;
    auto alloc = [&](size_t bytes) { void* r = p; p += (bytes + 255) & ~255ULL; return r; };
    float* norm_out = (float*)alloc((size_t)N * 4);
    float* norm_in  = (float*)alloc((size_t)N * 4);
    int* deg_in    = (int*)alloc((size_t)N * 4);
    int* row_start = (int*)alloc((size_t)(N + 1) * 4);
    int* cursor    = (int*)alloc((size_t)N * 4);
    int* blockSums = (int*)alloc((size_t)NB * 4);
    int* blockOffs = (int*)alloc((size_t)NB * 4);
    int* perm      = (int*)alloc((size_t)E * 4);
    float* agg1    = (float*)alloc((size_t)N * IN * 4);
    float* h1n     = (float*)alloc((size_t)N * HID * 4);
    float* h2      = agg1;

    // 8+8 privatized histograms overlap agg1 (consumed by reduce_norms
    // before gather_agg128 writes agg1): 16*N ints = 6.4 MB << N*IN*4.
    int* hist_out8 = (int*)agg1;
    int* hist_in8  = hist_out8 + 8 * (size_t)N;

    hipMemsetAsync(hist_out8, 0, 16 * (size_t)N * 4, stream);

    hist8_int<<<2048, 256, 0, stream>>>(src, dst, hist_out8, hist_in8, N, E);
    reduce_norms<<<(N + 255) / 256, 256, 0, stream>>>(
        hist_out8, hist_in8, deg_in, norm_out, norm_in, N);

    scan_block_sums<<<NB, 256, 0, stream>>>(deg_in, blockSums, N);
    scan_offsets<<<1, 64, 0, stream>>>(blockSums, blockOffs, NB, row_start, N, E);
    scan_write<<<NB, 256, 0, stream>>>(deg_in, blockOffs, row_start, cursor, N);

    fill_perm<<<(E + 255) / 256, 256, 0, stream>>>(src, dst, cursor, perm, E);

    gather_agg128<<<(N + 3) / 4, 256, 0, stream>>>(h, perm, row_start, norm_out, agg1, N);

    gemm_tiled<128, 8, 0><<<dim3((N + 127) / 128, HID / 128), 256, 0, stream>>>(
        agg1, W1, h1n, N, IN, HID, norm_in, norm_out, b1);

    gemm_tiled<64, 4, 1><<<dim3((N + 127) / 128, OUT / 64), 256, 0, stream>>>(
        h1n, W2, h2, N, HID, OUT, nullptr, nullptr, nullptr);

    gather_out64<<<(N + 3) / 4, 256, 0, stream>>>(h2, perm, row_start, norm_in, b2, out, N);
}

// Round 9
// 596.814 us; speedup vs baseline: 1.1347x; 1.1347x over previous
//
#include <hip/hip_runtime.h>

// ---------------------------------------------------------------------------
// GCN 2-layer forward, f32 — CSR-gather.
// Graph build: ONE atomic per edge per array does double duty:
//   rank[e] = atomicAdd(&deg_in[dst[e]], 1)   (histogram + stable rank)
// then scan(deg_in) -> row_start, and perm fill is ATOMIC-FREE:
//   perm[row_start[dst[e]] + rank[e]] = src[e]
// (Round-8 lesson: global atomics write through ~32B/op regardless of scope;
//  the only lever is issuing fewer of them.)
// ---------------------------------------------------------------------------

__global__ __launch_bounds__(256)
void rank_hist(const int* __restrict__ src, const int* __restrict__ dst,
               int* __restrict__ deg_out, int* __restrict__ deg_in,
               int* __restrict__ rank, int E)
{
    int e = blockIdx.x * 256 + threadIdx.x;
    if (e < E) {
        rank[e] = atomicAdd(&deg_in[dst[e]], 1);
        atomicAdd(&deg_out[src[e]], 1);
    }
}

// ---- 3-kernel exclusive scan over deg_in (chunk = 1024 elems/block) -------
__global__ __launch_bounds__(256)
void scan_block_sums(const int* __restrict__ deg, int* __restrict__ blockSums, int N)
{
    int t = threadIdx.x;
    int base = blockIdx.x * 1024 + t * 4;
    int s = 0;
    #pragma unroll
    for (int i = 0; i < 4; ++i) { int idx = base + i; if (idx < N) s += deg[idx]; }
    #pragma unroll
    for (int d = 32; d > 0; d >>= 1) s += __shfl_down(s, d);
    __shared__ int ws[4];
    int wid = t >> 6, lane = t & 63;
    if (lane == 0) ws[wid] = s;
    __syncthreads();
    if (t == 0) blockSums[blockIdx.x] = ws[0] + ws[1] + ws[2] + ws[3];
}

__global__ void scan_offsets(const int* __restrict__ blockSums, int* __restrict__ blockOffs,
                             int NB, int* __restrict__ row_start, int N, int E)
{
    if (threadIdx.x == 0 && blockIdx.x == 0) {
        int run = 0;
        for (int b = 0; b < NB; ++b) { blockOffs[b] = run; run += blockSums[b]; }
        row_start[N] = E;
    }
}

// writes row_start and (fused) norm_in = indeg^{-1/2}
__global__ __launch_bounds__(256)
void scan_write(const int* __restrict__ deg, const int* __restrict__ blockOffs,
                int* __restrict__ row_start, float* __restrict__ norm_in, int N)
{
    int t = threadIdx.x, lane = t & 63, wid = t >> 6;
    int base = blockIdx.x * 1024 + t * 4;
    int v[4]; int s = 0;
    #pragma unroll
    for (int i = 0; i < 4; ++i) {
        int idx = base + i;
        v[i] = (idx < N) ? deg[idx] : 0;
        s += v[i];
    }
    int x = s;
    #pragma unroll
    for (int d = 1; d < 64; d <<= 1) { int y = __shfl_up(x, d); if (lane >= d) x += y; }
    __shared__ int wtot[4];
    if (lane == 63) wtot[wid] = x;
    __syncthreads();
    int woff = 0;
    for (int w = 0; w < wid; ++w) woff += wtot[w];
    int run = (x - s) + woff + blockOffs[blockIdx.x];
    #pragma unroll
    for (int i = 0; i < 4; ++i) {
        int idx = base + i;
        if (idx < N) {
            row_start[idx] = run;
            norm_in[idx] = 1.0f / sqrtf((float)(v[i] > 1 ? v[i] : 1));
            run += v[i];
        }
    }
}

__global__ __launch_bounds__(256)
void norm_out_finalize(const int* __restrict__ deg, float* __restrict__ nrm, int n)
{
    int i = blockIdx.x * 256 + threadIdx.x;
    if (i < n) {
        int d = deg[i];
        nrm[i] = 1.0f / sqrtf((float)(d > 1 ? d : 1));
    }
}

// atomic-free perm fill: pos = row_start[dst] + rank
__global__ __launch_bounds__(256)
void fill_scatter(const int* __restrict__ src, const int* __restrict__ dst,
                  const int* __restrict__ rank, const int* __restrict__ row_start,
                  int* __restrict__ perm, int E)
{
    int e = blockIdx.x * 256 + threadIdx.x;
    if (e < E) {
        int d = dst[e];
        perm[row_start[d] + rank[e]] = src[e];
    }
}

// 128-ch gather: half-wave (32 lanes) x float4 covers one 512B row.
__global__ __launch_bounds__(256)
void gather_agg128(const float* __restrict__ X, const int* __restrict__ perm,
                   const int* __restrict__ row_start, const float* __restrict__ norm_out,
                   float* __restrict__ out, int N)
{
    int wid = threadIdx.x >> 6, lane = threadIdx.x & 63;
    int n = blockIdx.x * 4 + wid;
    if (n >= N) return;
    int half = lane >> 5;
    int sub  = lane & 31;
    const float4* X4 = (const float4*)X;
    int e = row_start[n], e1 = row_start[n + 1];
    float4 acc = make_float4(0.f, 0.f, 0.f, 0.f);

    for (; e + 4 <= e1; e += 4) {
        int a = perm[e + half];
        int b = perm[e + 2 + half];
        float wa = norm_out[a], wb = norm_out[b];
        float4 va = X4[(size_t)a * 32 + sub];
        float4 vb = X4[(size_t)b * 32 + sub];
        acc.x = fmaf(va.x, wa, fmaf(vb.x, wb, acc.x));
        acc.y = fmaf(va.y, wa, fmaf(vb.y, wb, acc.y));
        acc.z = fmaf(va.z, wa, fmaf(vb.z, wb, acc.z));
        acc.w = fmaf(va.w, wa, fmaf(vb.w, wb, acc.w));
    }
    for (; e + 2 <= e1; e += 2) {
        int a = perm[e + half];
        float wa = norm_out[a];
        float4 va = X4[(size_t)a * 32 + sub];
        acc.x = fmaf(va.x, wa, acc.x);
        acc.y = fmaf(va.y, wa, acc.y);
        acc.z = fmaf(va.z, wa, acc.z);
        acc.w = fmaf(va.w, wa, acc.w);
    }
    if (e < e1 && half == 0) {
        int a = perm[e];
        float wa = norm_out[a];
        float4 va = X4[(size_t)a * 32 + sub];
        acc.x = fmaf(va.x, wa, acc.x);
        acc.y = fmaf(va.y, wa, acc.y);
        acc.z = fmaf(va.z, wa, acc.z);
        acc.w = fmaf(va.w, wa, acc.w);
    }
    acc.x += __shfl_xor(acc.x, 32);
    acc.y += __shfl_xor(acc.y, 32);
    acc.z += __shfl_xor(acc.z, 32);
    acc.w += __shfl_xor(acc.w, 32);
    if (half == 0)
        ((float4*)out)[(size_t)n * 32 + sub] = acc;
}

// 64-ch gather: quarter-wave (16 lanes) x float4; fused *norm_in + bias.
__global__ __launch_bounds__(256)
void gather_out64(const float* __restrict__ X, const int* __restrict__ perm,
                  const int* __restrict__ row_start, const float* __restrict__ norm_in,
                  const float* __restrict__ bias, float* __restrict__ out, int N)
{
    int wid = threadIdx.x >> 6, lane = threadIdx.x & 63;
    int n = blockIdx.x * 4 + wid;
    if (n >= N) return;
    int q   = lane >> 4;
    int sub = lane & 15;
    const float4* X4 = (const float4*)X;
    int e = row_start[n], e1 = row_start[n + 1];
    float4 acc = make_float4(0.f, 0.f, 0.f, 0.f);

    for (; e + 8 <= e1; e += 8) {
        int a = perm[e + q];
        int b = perm[e + 4 + q];
        float4 va = X4[(size_t)a * 16 + sub];
        float4 vb = X4[(size_t)b * 16 + sub];
        acc.x += va.x + vb.x;
        acc.y += va.y + vb.y;
        acc.z += va.z + vb.z;
        acc.w += va.w + vb.w;
    }
    for (; e + 4 <= e1; e += 4) {
        int a = perm[e + q];
        float4 va = X4[(size_t)a * 16 + sub];
        acc.x += va.x; acc.y += va.y; acc.z += va.z; acc.w += va.w;
    }
    int r = e1 - e;      // 0..3
    if (q < r) {
        int a = perm[e + q];
        float4 va = X4[(size_t)a * 16 + sub];
        acc.x += va.x; acc.y += va.y; acc.z += va.z; acc.w += va.w;
    }
    acc.x += __shfl_xor(acc.x, 32);
    acc.y += __shfl_xor(acc.y, 32);
    acc.z += __shfl_xor(acc.z, 32);
    acc.w += __shfl_xor(acc.w, 32);
    acc.x += __shfl_xor(acc.x, 16);
    acc.y += __shfl_xor(acc.y, 16);
    acc.z += __shfl_xor(acc.z, 16);
    acc.w += __shfl_xor(acc.w, 16);
    if (q == 0) {
        float ni = norm_in[n];
        float4 bv = ((const float4*)bias)[sub];
        float4 o;
        o.x = fmaf(acc.x, ni, bv.x);
        o.y = fmaf(acc.y, ni, bv.y);
        o.z = fmaf(acc.z, ni, bv.z);
        o.w = fmaf(acc.w, ni, bv.w);
        ((float4*)out)[(size_t)n * 16 + sub] = o;
    }
}

// Tiled f32 GEMM: C[M,NC] = A[M,K]@B[K,NC]. BM=128, BK=16, 256 thr.
template<int BN, int TN, int EPI>
__global__ __launch_bounds__(256)
void gemm_tiled(const float* __restrict__ A, const float* __restrict__ B,
                float* __restrict__ C, int M, int K, int NC,
                const float* __restrict__ norm_in,
                const float* __restrict__ norm_out,
                const float* __restrict__ bias)
{
    __shared__ float As[16][132];
    __shared__ float Bs[16][BN];
    const int tid = threadIdx.x;
    const int tx = tid & 15;
    const int ty = tid >> 4;
    const int brow = blockIdx.x * 128;
    const int bcol = blockIdx.y * BN;

    const int ar = tid >> 2;
    const int ak = (tid & 3) * 4;

    float acc[8][TN] = {};

    for (int k0 = 0; k0 < K; k0 += 16) {
        #pragma unroll
        for (int hh = 0; hh < 2; ++hh) {
            int row = ar + hh * 64;
            int grow = brow + row;
            float4 v = make_float4(0.f, 0.f, 0.f, 0.f);
            if (grow < M) v = *(const float4*)(A + (size_t)grow * K + k0 + ak);
            As[ak + 0][row] = v.x;
            As[ak + 1][row] = v.y;
            As[ak + 2][row] = v.z;
            As[ak + 3][row] = v.w;
        }
        if (BN == 128) {
            #pragma unroll
            for (int hh = 0; hh < 2; ++hh) {
                int kr = (tid >> 5) + hh * 8;
                int cc = (tid & 31) * 4;
                *(float4*)&Bs[kr][cc] =
                    *(const float4*)(B + (size_t)(k0 + kr) * NC + bcol + cc);
            }
        } else {
            int kr = tid >> 4;
            int cc = (tid & 15) * 4;
            *(float4*)&Bs[kr][cc] =
                *(const float4*)(B + (size_t)(k0 + kr) * NC + bcol + cc);
        }
        __syncthreads();
        #pragma unroll
        for (int k = 0; k < 16; ++k) {
            float a0[8], b0[TN];
            *(float4*)&a0[0] = *(const float4*)&As[k][ty * 8];
            *(float4*)&a0[4] = *(const float4*)&As[k][ty * 8 + 4];
            *(float4*)&b0[0] = *(const float4*)&Bs[k][tx * TN];
            if (TN == 8)
                *(float4*)&b0[4] = *(const float4*)&Bs[k][tx * TN + 4];
            #pragma unroll
            for (int i = 0; i < 8; ++i)
                #pragma unroll
                for (int j = 0; j < TN; ++j)
                    acc[i][j] = fmaf(a0[i], b0[j], acc[i][j]);
        }
        __syncthreads();
    }

    #pragma unroll
    for (int i = 0; i < 8; ++i) {
        int row = brow + ty * 8 + i;
        if (row >= M) continue;
        float ni = 0.f, no = 0.f;
        if (EPI == 0) { ni = norm_in[row]; no = norm_out[row]; }
        #pragma unroll
        for (int j4 = 0; j4 < TN; j4 += 4) {
            int col = bcol + tx * TN + j4;
            float4 o = *(float4*)&acc[i][j4];
            if (EPI == 0) {
                o.x = fmaxf(fmaf(o.x, ni, bias[col + 0]), 0.0f) * no;
                o.y = fmaxf(fmaf(o.y, ni, bias[col + 1]), 0.0f) * no;
                o.z = fmaxf(fmaf(o.z, ni, bias[col + 2]), 0.0f) * no;
                o.w = fmaxf(fmaf(o.w, ni, bias[col + 3]), 0.0f) * no;
            }
            *(float4*)(C + (size_t)row * NC + col) = o;
        }
    }
}

extern "C" void kernel_launch(void* const* d_in, const int* in_sizes, int n_in,
                              void* d_out, int out_size, void* d_ws, size_t ws_size,
                              hipStream_t stream)
{
    const float* h   = (const float*)d_in[0];
    const int*   src = (const int*)d_in[1];
    const int*   dst = (const int*)d_in[2];
    const float* W1  = (const float*)d_in[3];
    const float* b1  = (const float*)d_in[4];
    const float* W2  = (const float*)d_in[5];
    const float* b2  = (const float*)d_in[6];
    float* out = (float*)d_out;

    const int HID = in_sizes[4];            // 256
    const int OUT = in_sizes[6];            // 64
    const int IN  = in_sizes[3] / HID;      // 128
    const int N   = in_sizes[0] / IN;       // 100000
    const int E   = in_sizes[1];            // 1600000
    const int NB  = (N + 1023) / 1024;

    char* p = (char*)d_ws;
    auto alloc = [&](size_t bytes) { void* r = p; p += (bytes + 255) & ~255ULL; return r; };
    float* norm_out = (float*)alloc((size_t)N * 4);
    float* norm_in  = (float*)alloc((size_t)N * 4);
    int* deg_out   = (int*)alloc((size_t)N * 4);
    int* deg_in    = (int*)alloc((size_t)N * 4);
    int* row_start = (int*)alloc((size_t)(N + 1) * 4);
    int* blockSums = (int*)alloc((size_t)NB * 4);
    int* blockOffs = (int*)alloc((size_t)NB * 4);
    int* perm      = (int*)alloc((size_t)E * 4);
    float* agg1    = (float*)alloc((size_t)N * IN * 4);
    float* h1n     = (float*)alloc((size_t)N * HID * 4);
    float* h2      = agg1;                  // reuse agg1 region for [N,OUT]
    int*   rank    = (int*)h1n;             // alias: consumed by fill_scatter
                                            // before gemm_tiled<0> writes h1n

    // zero deg_out + deg_in (contiguous region between the two pointers)
    hipMemsetAsync(deg_out, 0, (size_t)((char*)row_start - (char*)deg_out), stream);

    // 1. one atomic per edge per array: rank + both histograms
    rank_hist<<<(E + 255) / 256, 256, 0, stream>>>(src, dst, deg_out, deg_in, rank, E);

    // 2. exclusive scan deg_in -> row_start (+ fused norm_in)
    scan_block_sums<<<NB, 256, 0, stream>>>(deg_in, blockSums, N);
    scan_offsets<<<1, 64, 0, stream>>>(blockSums, blockOffs, NB, row_start, N, E);
    scan_write<<<NB, 256, 0, stream>>>(deg_in, blockOffs, row_start, norm_in, N);
    norm_out_finalize<<<(N + 255) / 256, 256, 0, stream>>>(deg_out, norm_out, N);

    // 3. atomic-free perm fill
    fill_scatter<<<(E + 255) / 256, 256, 0, stream>>>(src, dst, rank, row_start, perm, E);

    // 4. layer-1 aggregation (gather)
    gather_agg128<<<(N + 3) / 4, 256, 0, stream>>>(h, perm, row_start, norm_out, agg1, N);

    // 5. layer-1 projection + epilogue
    gemm_tiled<128, 8, 0><<<dim3((N + 127) / 128, HID / 128), 256, 0, stream>>>(
        agg1, W1, h1n, N, IN, HID, norm_in, norm_out, b1);

    // 6. layer-2 projection
    gemm_tiled<64, 4, 1><<<dim3((N + 127) / 128, OUT / 64), 256, 0, stream>>>(
        h1n, W2, h2, N, HID, OUT, nullptr, nullptr, nullptr);

    // 7. layer-2 aggregation + fused epilogue -> d_out
    gather_out64<<<(N + 3) / 4, 256, 0, stream>>>(h2, perm, row_start, norm_in, b2, out, N);
}